// Round 11
// baseline (108.824 us; speedup 1.0000x reference)
//
#include <hip/hip_runtime.h>

#define N 64
#define NPAD 65
#define ITERS 50
#define TEMP 12.5f
#define WEPS 1e-5f
#define QDIM 75
#define WDIM 5

typedef __attribute__((ext_vector_type(8))) short bf16x8;   // MFMA A/B frag (4 VGPRs)
typedef __attribute__((ext_vector_type(4))) float f32x4;    // MFMA C/D frag

// v_cvt_pk_bf16_f32: no builtin on gfx950 (T12 note) -> inline asm. Any
// lo/hi-order convention cancels: A and B frags are built with the SAME map.
static __device__ __forceinline__ unsigned cvt_pk(float lo, float hi) {
    unsigned r;
    asm("v_cvt_pk_bf16_f32 %0, %1, %2" : "=v"(r) : "v"(lo), "v"(hi));
    return r;
}
union FragU { unsigned u[4]; bf16x8 v; };
static __device__ __forceinline__ bf16x8 pack8(const float e[8]) {
    FragU f;
    f.u[0] = cvt_pk(e[0], e[1]);
    f.u[1] = cvt_pk(e[2], e[3]);
    f.u[2] = cvt_pk(e[4], e[5]);
    f.u[3] = cvt_pk(e[6], e[7]);
    return f.v;
}

__device__ __forceinline__ float waveReduceSum(float x) {
#pragma unroll
    for (int off = 32; off; off >>= 1) x += __shfl_xor(x, off, 64);
    return x;
}

// One wave per problem; matvecs on the MFMA pipe (idle in R1-R10).
// A-frag (16x16x32 bf16): lane l holds A[l&15][(l>>4)*8+j], j=0..7.
// B built with v REPLICATED across all 16 cols -> col layout irrelevant and
// every C column equals K.v; C layout (m89-verified): col=lane&15,
// row=(lane>>4)*4+reg -> lanes with (lane&15)==0 write the 64 row-sums.
__global__ __launch_bounds__(64, 1) void emd_mfma(
    const float* __restrict__ sim,   // [B, 64, 64]
    const float* __restrict__ w1,    // [B, N]
    const float* __restrict__ w2,    // [E, W, Q, N] (transposed Q/W)
    float* __restrict__ out,         // [B]
    int B)
{
    __shared__ float S[N * NPAD];
    __shared__ __align__(16) float SUM[N], U[N], V[N];

    const int lane = threadIdx.x;
    const int b    = blockIdx.x;
    const int q    = lane >> 4;     // k-slot group
    const int m    = lane & 15;     // row/col within 16-block
    const float* gm = sim + (size_t)b * N * N;

    // ---- stage sim into padded LDS (coalesced float4) ----
    const float4* g4 = (const float4*)gm;
#pragma unroll
    for (int t = 0; t < 16; ++t) {
        float4 x = g4[t * 64 + lane];
        int idx = t * 64 + lane;
        int r = idx >> 4;
        int c = (idx & 15) * 4;
        S[r * NPAD + c + 0] = x.x;
        S[r * NPAD + c + 1] = x.y;
        S[r * NPAD + c + 2] = x.z;
        S[r * NPAD + c + 3] = x.w;
    }
    __syncthreads();

    // ---- K and K^T as MFMA A-fragments, bf16, register-resident ----
    // KA[rb][c]: A = K[16rb+m][32c+8q+j];  KT[rb][c]: A = K[32c+8q+j][16rb+m]
    bf16x8 KA[4][2], KT[4][2];
#pragma unroll
    for (int rb = 0; rb < 4; ++rb)
#pragma unroll
        for (int c = 0; c < 2; ++c) {
            float e[8];
            const float* p = &S[(16 * rb + m) * NPAD + 32 * c + 8 * q];
#pragma unroll
            for (int j = 0; j < 8; ++j) e[j] = __expf((p[j] - 1.0f) * 20.0f);
            KA[rb][c] = pack8(e);
#pragma unroll
            for (int j = 0; j < 8; ++j)
                e[j] = __expf((S[(32 * c + 8 * q + j) * NPAD + 16 * rb + m] - 1.0f) * 20.0f);
            KT[rb][c] = pack8(e);
        }
#pragma unroll
    for (int rb = 0; rb < 4; ++rb)
#pragma unroll
        for (int c = 0; c < 2; ++c) {
            asm volatile("" : "+v"(KA[rb][c]));
            asm volatile("" : "+v"(KT[rb][c]));
        }

    // ---- marginals: lane owns its row/col value ----
    float a_own = w1[(size_t)b * N + lane];
    a_own = fmaxf(a_own, 0.0f) + WEPS;
    a_own *= (float)N / waveReduceSum(a_own);

    const int e_  = b / (QDIM * WDIM);
    const int rm  = b % (QDIM * WDIM);
    const int qq  = rm / WDIM, w = rm % WDIM;
    float b_own = w2[((((size_t)e_ * WDIM + w) * QDIM) + qq) * N + lane];
    b_own = fmaxf(b_own, 0.0f) + WEPS;
    b_own *= (float)N / waveReduceSum(b_own);

    V[lane] = 1.0f;
    __syncthreads();

    float u_own = 0.0f;
#pragma unroll 1
    for (int it = 0; it < ITERS; ++it) {
        // ---- u-phase: u = a ∘ rcp(K v) ----
        {
            const float4* p0 = (const float4*)&V[8 * q];        // v[8q..8q+7] (bcast)
            const float4* p1 = (const float4*)&V[32 + 8 * q];
            float4 x0 = p0[0], x1 = p0[1], y0 = p1[0], y1 = p1[1];
            float e0[8] = {x0.x, x0.y, x0.z, x0.w, x1.x, x1.y, x1.z, x1.w};
            float e1[8] = {y0.x, y0.y, y0.z, y0.w, y1.x, y1.y, y1.z, y1.w};
            bf16x8 B0 = pack8(e0), B1 = pack8(e1);
            f32x4 acc[4];
#pragma unroll
            for (int rb = 0; rb < 4; ++rb)
                acc[rb] = __builtin_amdgcn_mfma_f32_16x16x32_bf16(KA[rb][1], B1, (f32x4){0.f, 0.f, 0.f, 0.f}, 0, 0, 0);
#pragma unroll
            for (int rb = 0; rb < 4; ++rb)
                acc[rb] = __builtin_amdgcn_mfma_f32_16x16x32_bf16(KA[rb][0], B0, acc[rb], 0, 0, 0);
            if (m == 0) {
#pragma unroll
                for (int rb = 0; rb < 4; ++rb)
                    *(f32x4*)&SUM[16 * rb + 4 * q] = acc[rb];   // C col 0: rows 16rb+4q+reg
            }
        }
        __syncthreads();
        u_own = a_own * __builtin_amdgcn_rcpf(SUM[lane]);
        U[lane] = u_own;
        __syncthreads();

        // ---- v-phase: v = b ∘ rcp(K^T u) ----
        {
            const float4* p0 = (const float4*)&U[8 * q];
            const float4* p1 = (const float4*)&U[32 + 8 * q];
            float4 x0 = p0[0], x1 = p0[1], y0 = p1[0], y1 = p1[1];
            float e0[8] = {x0.x, x0.y, x0.z, x0.w, x1.x, x1.y, x1.z, x1.w};
            float e1[8] = {y0.x, y0.y, y0.z, y0.w, y1.x, y1.y, y1.z, y1.w};
            bf16x8 B0 = pack8(e0), B1 = pack8(e1);
            f32x4 acc[4];
#pragma unroll
            for (int rb = 0; rb < 4; ++rb)
                acc[rb] = __builtin_amdgcn_mfma_f32_16x16x32_bf16(KT[rb][1], B1, (f32x4){0.f, 0.f, 0.f, 0.f}, 0, 0, 0);
#pragma unroll
            for (int rb = 0; rb < 4; ++rb)
                acc[rb] = __builtin_amdgcn_mfma_f32_16x16x32_bf16(KT[rb][0], B0, acc[rb], 0, 0, 0);
            if (m == 0) {
#pragma unroll
                for (int rb = 0; rb < 4; ++rb)
                    *(f32x4*)&SUM[16 * rb + 4 * q] = acc[rb];
            }
        }
        __syncthreads();
        V[lane] = b_own * __builtin_amdgcn_rcpf(SUM[lane]);
        __syncthreads();
    }

    // ---- score = sum_ij u_i K_ij sim_ij v_j  (f32 K/sim from LDS) ----
    {
        float p0 = 0, p1 = 0;
#pragma unroll
        for (int j4 = 0; j4 < 16; ++j4) {
            float4 vv = *(const float4*)&V[4 * j4];
            float4 ss = *(const float4*)&S[lane * NPAD + 4 * j4];
            float k0 = __expf((ss.x - 1.0f) * 20.0f);
            float k1 = __expf((ss.y - 1.0f) * 20.0f);
            float k2 = __expf((ss.z - 1.0f) * 20.0f);
            float k3 = __expf((ss.w - 1.0f) * 20.0f);
            p0 = fmaf(k0 * ss.x, vv.x, p0);
            p1 = fmaf(k1 * ss.y, vv.y, p1);
            p0 = fmaf(k2 * ss.z, vv.z, p0);
            p1 = fmaf(k3 * ss.w, vv.w, p1);
        }
        float tot = waveReduceSum(u_own * (p0 + p1));
        if (lane == 0) out[b] = tot * (TEMP / (float)N);
    }
}

extern "C" void kernel_launch(void* const* d_in, const int* in_sizes, int n_in,
                              void* d_out, int out_size, void* d_ws, size_t ws_size,
                              hipStream_t stream) {
    const float* sim = (const float*)d_in[0];
    const float* w1  = (const float*)d_in[1];
    const float* w2  = (const float*)d_in[2];
    float* out       = (float*)d_out;
    const int B = in_sizes[0] / (N * N);   // 1500
    emd_mfma<<<B, 64, 0, stream>>>(sim, w1, w2, out, B);
}

// Round 13
// 103.418 us; speedup vs baseline: 1.0523x; 1.0523x over previous
//
#include <hip/hip_runtime.h>

#define N 64
#define NPAD 65
#define ITERS 50
#define TEMP 12.5f
#define WEPS 1e-5f
#define QDIM 75
#define WDIM 5

typedef __attribute__((ext_vector_type(8))) short bf16x8;   // MFMA A/B frag (4 VGPRs)
typedef __attribute__((ext_vector_type(4))) float f32x4;    // MFMA C/D frag

static __device__ __forceinline__ unsigned cvt_pk(float lo, float hi) {
    unsigned r;
    asm("v_cvt_pk_bf16_f32 %0, %1, %2" : "=v"(r) : "v"(lo), "v"(hi));
    return r;
}
union FragU { unsigned u[4]; bf16x8 v; };
static __device__ __forceinline__ bf16x8 pack8(const float e[8]) {
    FragU f;
    f.u[0] = cvt_pk(e[0], e[1]);
    f.u[1] = cvt_pk(e[2], e[3]);
    f.u[2] = cvt_pk(e[4], e[5]);
    f.u[3] = cvt_pk(e[6], e[7]);
    return f.v;
}

__device__ __forceinline__ float waveReduceSum(float x) {
#pragma unroll
    for (int off = 32; off; off >>= 1) x += __shfl_xor(x, off, 64);
    return x;
}

// MFMA Sinkhorn, verified-primitives-only, ONE LDS round-trip per phase.
// After C = K·[v..v] (R11-verified layout: row = 16rb + 4*(lane>>4) + reg,
// all 16 cols equal): lane L holds s[sig(L)] at acc[(L>>2)&3][L&3], where
// sig(L) = ((L>>2)&3)*16 + (L>>4)*4 + (L&3) (involution). Select it with a
// cndmask tree, u = a[sig]*rcp(s), ds_write U[sig(L)] (bijective -> 2/bank,
// free), barrier, b128-read the B-fragment slices, cvt_pk, next MFMA.
__global__ __launch_bounds__(64, 1) void emd_mfma2(
    const float* __restrict__ sim,   // [B, 64, 64]
    const float* __restrict__ w1,    // [B, N]
    const float* __restrict__ w2,    // [E, W, Q, N] (transposed Q/W)
    float* __restrict__ out,         // [B]
    int B)
{
    __shared__ float S[N * NPAD];
    __shared__ __align__(16) float U[N], V[N], Am[N], Bm[N];

    const int lane = threadIdx.x;
    const int b    = blockIdx.x;
    const int q    = lane >> 4;     // k-slot group
    const int m    = lane & 15;     // row/col within 16-block
    const float* gm = sim + (size_t)b * N * N;

    // ---- stage sim into padded LDS (coalesced float4) ----
    const float4* g4 = (const float4*)gm;
#pragma unroll
    for (int t = 0; t < 16; ++t) {
        float4 x = g4[t * 64 + lane];
        int idx = t * 64 + lane;
        int r = idx >> 4;
        int c = (idx & 15) * 4;
        S[r * NPAD + c + 0] = x.x;
        S[r * NPAD + c + 1] = x.y;
        S[r * NPAD + c + 2] = x.z;
        S[r * NPAD + c + 3] = x.w;
    }
    __syncthreads();

    // ---- K and K^T as MFMA A-fragments (R11-verified mapping) ----
    bf16x8 KA[4][2], KT[4][2];
#pragma unroll
    for (int rb = 0; rb < 4; ++rb)
#pragma unroll
        for (int c = 0; c < 2; ++c) {
            float e[8];
            const float* p = &S[(16 * rb + m) * NPAD + 32 * c + 8 * q];
#pragma unroll
            for (int j = 0; j < 8; ++j) e[j] = __expf((p[j] - 1.0f) * 20.0f);
            KA[rb][c] = pack8(e);
#pragma unroll
            for (int j = 0; j < 8; ++j)
                e[j] = __expf((S[(32 * c + 8 * q + j) * NPAD + 16 * rb + m] - 1.0f) * 20.0f);
            KT[rb][c] = pack8(e);
        }
#pragma unroll
    for (int rb = 0; rb < 4; ++rb)
#pragma unroll
        for (int c = 0; c < 2; ++c) {
            asm volatile("" : "+v"(KA[rb][c]));
            asm volatile("" : "+v"(KT[rb][c]));
        }

    // ---- marginals (lane owns its value), stored to LDS for sig-gather ----
    float a_own = w1[(size_t)b * N + lane];
    a_own = fmaxf(a_own, 0.0f) + WEPS;
    a_own *= (float)N / waveReduceSum(a_own);
    Am[lane] = a_own;

    const int e_  = b / (QDIM * WDIM);
    const int rm  = b % (QDIM * WDIM);
    const int qq  = rm / WDIM, w = rm % WDIM;
    float b_own = w2[((((size_t)e_ * WDIM + w) * QDIM) + qq) * N + lane];
    b_own = fmaxf(b_own, 0.0f) + WEPS;
    b_own *= (float)N / waveReduceSum(b_own);
    Bm[lane] = b_own;
    __syncthreads();

    // sigma: which row/col index this lane's selected acc value belongs to
    const int sig = ((lane >> 2) & 3) * 16 + (lane >> 4) * 4 + (lane & 3);
    const float a_sig = Am[sig];
    const float b_sig = Bm[sig];
    const bool s0 = lane & 1, s1 = lane & 2, s2 = lane & 4, s3 = lane & 8;

    // initial B-frags: v = 1
    float ones[8] = {1, 1, 1, 1, 1, 1, 1, 1};
    bf16x8 B0 = pack8(ones), B1 = pack8(ones);

#pragma unroll 1
    for (int it = 0; it < ITERS; ++it) {
        // ===== u-phase: u = a ∘ rcp(K v) =====
        {
            f32x4 acc[4];
#pragma unroll
            for (int rb = 0; rb < 4; ++rb)
                acc[rb] = __builtin_amdgcn_mfma_f32_16x16x32_bf16(KA[rb][1], B1, (f32x4){0.f, 0.f, 0.f, 0.f}, 0, 0, 0);
#pragma unroll
            for (int rb = 0; rb < 4; ++rb)
                acc[rb] = __builtin_amdgcn_mfma_f32_16x16x32_bf16(KA[rb][0], B0, acc[rb], 0, 0, 0);
            // x = acc[(lane>>2)&3][lane&3] = s[sig(lane)]
            float t0 = s1 ? (s0 ? acc[0][3] : acc[0][2]) : (s0 ? acc[0][1] : acc[0][0]);
            float t1 = s1 ? (s0 ? acc[1][3] : acc[1][2]) : (s0 ? acc[1][1] : acc[1][0]);
            float t2 = s1 ? (s0 ? acc[2][3] : acc[2][2]) : (s0 ? acc[2][1] : acc[2][0]);
            float t3 = s1 ? (s0 ? acc[3][3] : acc[3][2]) : (s0 ? acc[3][1] : acc[3][0]);
            float x  = s3 ? (s2 ? t3 : t2) : (s2 ? t1 : t0);
            U[sig] = a_sig * __builtin_amdgcn_rcpf(x);
        }
        __syncthreads();
        {
            float4 x0 = *(const float4*)&U[8 * q];
            float4 x1 = *(const float4*)&U[8 * q + 4];
            float4 y0 = *(const float4*)&U[32 + 8 * q];
            float4 y1 = *(const float4*)&U[32 + 8 * q + 4];
            float e0[8] = {x0.x, x0.y, x0.z, x0.w, x1.x, x1.y, x1.z, x1.w};
            float e1[8] = {y0.x, y0.y, y0.z, y0.w, y1.x, y1.y, y1.z, y1.w};
            B0 = pack8(e0);
            B1 = pack8(e1);
        }

        // ===== v-phase: v = b ∘ rcp(K^T u) =====
        {
            f32x4 acc[4];
#pragma unroll
            for (int rb = 0; rb < 4; ++rb)
                acc[rb] = __builtin_amdgcn_mfma_f32_16x16x32_bf16(KT[rb][1], B1, (f32x4){0.f, 0.f, 0.f, 0.f}, 0, 0, 0);
#pragma unroll
            for (int rb = 0; rb < 4; ++rb)
                acc[rb] = __builtin_amdgcn_mfma_f32_16x16x32_bf16(KT[rb][0], B0, acc[rb], 0, 0, 0);
            float t0 = s1 ? (s0 ? acc[0][3] : acc[0][2]) : (s0 ? acc[0][1] : acc[0][0]);
            float t1 = s1 ? (s0 ? acc[1][3] : acc[1][2]) : (s0 ? acc[1][1] : acc[1][0]);
            float t2 = s1 ? (s0 ? acc[2][3] : acc[2][2]) : (s0 ? acc[2][1] : acc[2][0]);
            float t3 = s1 ? (s0 ? acc[3][3] : acc[3][2]) : (s0 ? acc[3][1] : acc[3][0]);
            float x  = s3 ? (s2 ? t3 : t2) : (s2 ? t1 : t0);
            V[sig] = b_sig * __builtin_amdgcn_rcpf(x);
        }
        __syncthreads();
        {
            float4 x0 = *(const float4*)&V[8 * q];
            float4 x1 = *(const float4*)&V[8 * q + 4];
            float4 y0 = *(const float4*)&V[32 + 8 * q];
            float4 y1 = *(const float4*)&V[32 + 8 * q + 4];
            float e0[8] = {x0.x, x0.y, x0.z, x0.w, x1.x, x1.y, x1.z, x1.w};
            float e1[8] = {y0.x, y0.y, y0.z, y0.w, y1.x, y1.y, y1.z, y1.w};
            B0 = pack8(e0);
            B1 = pack8(e1);
        }
    }

    // ---- epilogue: score = sum_ij u_i K_ij sim_ij v_j (f32 from LDS) ----
    {
        float u_own = U[lane];
        float p0 = 0, p1 = 0;
#pragma unroll
        for (int j4 = 0; j4 < 16; ++j4) {
            float4 vv = *(const float4*)&V[4 * j4];
            float4 ss = *(const float4*)&S[lane * NPAD + 4 * j4];
            float k0 = __expf((ss.x - 1.0f) * 20.0f);
            float k1 = __expf((ss.y - 1.0f) * 20.0f);
            float k2 = __expf((ss.z - 1.0f) * 20.0f);
            float k3 = __expf((ss.w - 1.0f) * 20.0f);
            p0 = fmaf(k0 * ss.x, vv.x, p0);
            p1 = fmaf(k1 * ss.y, vv.y, p1);
            p0 = fmaf(k2 * ss.z, vv.z, p0);
            p1 = fmaf(k3 * ss.w, vv.w, p1);
        }
        float tot = waveReduceSum(u_own * (p0 + p1));
        if (lane == 0) out[b] = tot * (TEMP / (float)N);
    }
}

extern "C" void kernel_launch(void* const* d_in, const int* in_sizes, int n_in,
                              void* d_out, int out_size, void* d_ws, size_t ws_size,
                              hipStream_t stream) {
    const float* sim = (const float*)d_in[0];
    const float* w1  = (const float*)d_in[1];
    const float* w2  = (const float*)d_in[2];
    float* out       = (float*)d_out;
    const int B = in_sizes[0] / (N * N);   // 1500
    emd_mfma2<<<B, 64, 0, stream>>>(sim, w1, w2, out, B);
}